// Round 1
// baseline (180.337 us; speedup 1.0000x reference)
//
#include <hip/hip_runtime.h>
#include <hip/hip_bf16.h>

#define LL 2048
#define DD 64
#define BQ 64
#define BK 64
#define NEGV -1000000000.0f

typedef __attribute__((ext_vector_type(4))) float  f32x4;
typedef __attribute__((ext_vector_type(8))) short  short8;
typedef __attribute__((ext_vector_type(4))) short  short4v;

// fp32 -> bf16 round-to-nearest-even (inputs are normal floats)
__device__ __forceinline__ short f2bf(float f) {
  unsigned u = __builtin_bit_cast(unsigned, f);
  unsigned r = (u + 0x7fffu + ((u >> 16) & 1u)) >> 16;
  return (short)r;
}

__global__ __launch_bounds__(256, 2)
void attn_kernel(const float* __restrict__ q, const float* __restrict__ k,
                 const float* __restrict__ v, const int* __restrict__ mask,
                 float* __restrict__ out) {
  // LDS tiles, all XOR-swizzled: elem = row*64 + (col ^ ((row&7)<<3))
  __shared__ short Qs[BQ * DD];        // Qs[qrow][d]
  __shared__ short Kt[BK * DD];        // Kt[e][dd]   (K2 reshaped matrix, transposed)
  __shared__ short Vt[DD * BK];        // Vt[d][key]
  __shared__ short Ps[4][16 * BK];     // per-wave P tile [q][key]

  const int t    = threadIdx.x;
  const int lane = t & 63;
  const int wq   = t >> 6;             // wave 0..3
  const int lo16 = lane & 15;
  const int hi4  = lane >> 4;

  const int bx = blockIdx.x;
  const int qt = bx & 31;              // q tile index
  const int hd = bx >> 5;              // b*16 + h
  const int b  = hd >> 4;

  const size_t base = (size_t)hd * LL * DD;
  const int q0 = qt * BQ;

  // ---- stage Q (once): 16 floats per thread ----
  {
    const int r  = t >> 2;             // 0..63
    const int c0 = (t & 3) << 4;       // 0,16,32,48
    const float* src = q + base + (size_t)(q0 + r) * DD + c0;
    const int sw = (r & 7) << 3;
#pragma unroll
    for (int j = 0; j < 16; j += 4) {
      f32x4 f = *(const f32x4*)(src + j);
      short4v s;
      s.x = f2bf(f.x); s.y = f2bf(f.y); s.z = f2bf(f.z); s.w = f2bf(f.w);
      *(short4v*)&Qs[r * DD + ((c0 + j) ^ sw)] = s;
    }
  }
  __syncthreads();

  // Q fragments hoisted to registers: A[i=q][k=d], i=lane&15, k = hi4*8 + slice*32
  short8 aq[2];
  {
    int qr = wq * 16 + lo16;
    int sw = (qr & 7) << 3;
#pragma unroll
    for (int s = 0; s < 2; ++s) {
      int c = s * 32 + hi4 * 8;
      aq[s] = *(const short8*)&Qs[qr * DD + (c ^ sw)];
    }
  }

  f32x4 O[4] = {};                     // O[dsub]: row=hi4*4+reg (q), col=dsub*16+lo16 (d)
  float m[4], lsum[4];
#pragma unroll
  for (int r = 0; r < 4; ++r) { m[r] = -INFINITY; lsum[r] = 0.f; }

  const float scale = 0.125f;          // 1/sqrt(64)
  const int r64  = t >> 2;             // staging row 0..63
  const int c016 = (t & 3) << 4;

  for (int kt = 0; kt < LL / BK; ++kt) {
    // stage Kt[e][dd] <- K2[dd][e] = k[base + dd*LL + kt*BK + e]
    {
      const float* src = k + base + (size_t)r64 * LL + kt * BK + c016;
#pragma unroll
      for (int j = 0; j < 16; j += 4) {
        f32x4 f = *(const f32x4*)(src + j);
#pragma unroll
        for (int i = 0; i < 4; ++i) {
          int e = c016 + j + i;
          Kt[e * DD + (r64 ^ ((e & 7) << 3))] = f2bf(f[i]);
        }
      }
    }
    // stage Vt[d][key] <- v[base + (kt*BK+key)*DD + d]
    {
      const float* src = v + base + (size_t)(kt * BK + r64) * DD + c016;
#pragma unroll
      for (int j = 0; j < 16; j += 4) {
        f32x4 f = *(const f32x4*)(src + j);
#pragma unroll
        for (int i = 0; i < 4; ++i) {
          int d = c016 + j + i;
          Vt[d * BK + (r64 ^ ((d & 7) << 3))] = f2bf(f[i]);
        }
      }
    }
    __syncthreads();

    // QK: S[16 q][64 e], 4 key-subtiles x 2 K-slices
    f32x4 S[4];
#pragma unroll
    for (int sub = 0; sub < 4; ++sub) {
      f32x4 acc = {};
      int e  = sub * 16 + lo16;
      int sw = (e & 7) << 3;
#pragma unroll
      for (int s = 0; s < 2; ++s) {
        int c = s * 32 + hi4 * 8;
        short8 bk = *(const short8*)&Kt[e * DD + (c ^ sw)];
        acc = __builtin_amdgcn_mfma_f32_16x16x32_bf16(aq[s], bk, acc, 0, 0, 0);
      }
      S[sub] = acc;
    }

    // scale + mask (mask==0 -> exactly NEG, matching reference order)
    const int kbase = kt * BK;
#pragma unroll
    for (int sub = 0; sub < 4; ++sub) {
#pragma unroll
      for (int r = 0; r < 4; ++r) {
        int qg = q0 + wq * 16 + hi4 * 4 + r;
        int kg = kbase + sub * 16 + lo16;
        int mv = mask[(size_t)b * LL * LL + (size_t)qg * LL + kg];
        float s = S[sub][r] * scale;
        S[sub][r] = (mv == 0) ? NEGV : s;
      }
    }

    // row max over 64 keys (4 subtiles in-lane, 16-lane group via shfl_xor)
    float mt[4];
#pragma unroll
    for (int r = 0; r < 4; ++r) {
      float x = fmaxf(fmaxf(S[0][r], S[1][r]), fmaxf(S[2][r], S[3][r]));
      x = fmaxf(x, __shfl_xor(x, 1));
      x = fmaxf(x, __shfl_xor(x, 2));
      x = fmaxf(x, __shfl_xor(x, 4));
      x = fmaxf(x, __shfl_xor(x, 8));
      mt[r] = x;
    }

    // online-softmax update
#pragma unroll
    for (int r = 0; r < 4; ++r) {
      float mnew = fmaxf(m[r], mt[r]);
      float fac  = __expf(m[r] - mnew);
      m[r] = mnew;
      lsum[r] *= fac;
#pragma unroll
      for (int sub = 0; sub < 4; ++sub) O[sub][r] *= fac;
    }

    // P = exp(S - m) -> bf16 -> per-wave LDS tile (relayout for PV A-operand)
#pragma unroll
    for (int sub = 0; sub < 4; ++sub) {
#pragma unroll
      for (int r = 0; r < 4; ++r) {
        float p = __expf(S[sub][r] - m[r]);
        lsum[r] += p;
        int qr = hi4 * 4 + r;
        int kg = sub * 16 + lo16;
        Ps[wq][qr * BK + (kg ^ ((qr & 7) << 3))] = f2bf(p);
      }
    }
    __syncthreads();

    // PV: O[16 q][64 d] += P[16 q][64 key] * V[64 key][64 d]
    short8 ap[2];
    {
      int qr = lo16;
      int sw = (qr & 7) << 3;
#pragma unroll
      for (int s = 0; s < 2; ++s) {
        int c = s * 32 + hi4 * 8;
        ap[s] = *(const short8*)&Ps[wq][qr * BK + (c ^ sw)];
      }
    }
#pragma unroll
    for (int sub = 0; sub < 4; ++sub) {
      int d  = sub * 16 + lo16;
      int sw = (d & 7) << 3;
#pragma unroll
      for (int s = 0; s < 2; ++s) {
        int c = s * 32 + hi4 * 8;
        short8 bv = *(const short8*)&Vt[d * BK + (c ^ sw)];
        O[sub] = __builtin_amdgcn_mfma_f32_16x16x32_bf16(ap[s], bv, O[sub], 0, 0, 0);
      }
    }
    __syncthreads();  // protect Kt/Vt/Ps before next stage
  }

  // epilogue: reduce l across the 16-lane group, normalize, store fp32
#pragma unroll
  for (int r = 0; r < 4; ++r) {
    float x = lsum[r];
    x += __shfl_xor(x, 1);
    x += __shfl_xor(x, 2);
    x += __shfl_xor(x, 4);
    x += __shfl_xor(x, 8);
    lsum[r] = 1.f / x;
  }
#pragma unroll
  for (int sub = 0; sub < 4; ++sub) {
#pragma unroll
    for (int r = 0; r < 4; ++r) {
      int qg = q0 + wq * 16 + hi4 * 4 + r;
      int dg = sub * 16 + lo16;
      out[base + (size_t)qg * DD + dg] = O[sub][r] * lsum[r];
    }
  }
}

extern "C" void kernel_launch(void* const* d_in, const int* in_sizes, int n_in,
                              void* d_out, int out_size, void* d_ws, size_t ws_size,
                              hipStream_t stream) {
  const float* q    = (const float*)d_in[0];
  const float* k    = (const float*)d_in[1];
  const float* v    = (const float*)d_in[2];
  const int*   mask = (const int*)d_in[3];
  float* out = (float*)d_out;

  dim3 grid(32 * (LL / BQ));   // (B*H) * q-tiles = 32 * 32 = 1024
  dim3 block(256);
  attn_kernel<<<grid, block, 0, stream>>>(q, k, v, mask, out);
}

// Round 2
// 115.778 us; speedup vs baseline: 1.5576x; 1.5576x over previous
//
#include <hip/hip_runtime.h>
#include <hip/hip_bf16.h>
#include <stdint.h>

#define LL 2048
#define DD 64
#define BK 64
#define NEGV -1000000000.0f

typedef __attribute__((ext_vector_type(4))) float f32x4;
typedef __attribute__((ext_vector_type(8))) short short8;
typedef __attribute__((ext_vector_type(4))) int   int4v;

#define AS3 __attribute__((address_space(3)))
#define AS1 __attribute__((address_space(1)))

// fp32 -> bf16 round-to-nearest-even
__device__ __forceinline__ short f2bf(float f) {
  unsigned u = __builtin_bit_cast(unsigned, f);
  return (short)((u + 0x7fffu + ((u >> 16) & 1u)) >> 16);
}

// ---------------- prepass: K transpose, V transpose, mask bit-pack ----------
// blocks 0..1023:    K2[d][e] (reshape view) -> ktg[head][e][d]   bf16
// blocks 1024..2047: V[key][d]               -> vtg[head][d][key] bf16
// blocks 2048..3071: mask int32 -> 1 bit per element, mp[b][row][64 words]
__global__ __launch_bounds__(256, 4)
void prep_kernel(const float* __restrict__ k, const float* __restrict__ v,
                 const int* __restrict__ mask, short* __restrict__ ktg,
                 short* __restrict__ vtg, unsigned* __restrict__ mp) {
  __shared__ short Ts[64 * 64];
  const int bid = blockIdx.x;
  const int t = threadIdx.x;

  if (bid < 2048) {
    const bool isK = (bid < 1024);
    const int id   = isK ? bid : bid - 1024;
    const int hd   = id >> 5;
    const int tile = id & 31;
    const size_t base = (size_t)hd * LL * DD;

    const int r  = t >> 2;           // 0..63
    const int c0 = (t & 3) << 4;     // 0,16,32,48
    // K: row d=r (stride LL), cols e = tile*64 + c0..+15
    // V: row key=tile*64+r (stride DD), cols d = c0..+15
    const float* src = isK ? (k + base + (size_t)r * LL + tile * 64 + c0)
                           : (v + base + (size_t)(tile * 64 + r) * DD + c0);
#pragma unroll
    for (int j = 0; j < 16; j += 4) {
      f32x4 f = *(const f32x4*)(src + j);
#pragma unroll
      for (int i2 = 0; i2 < 4; ++i2)
        Ts[(c0 + j + i2) * 64 + r] = f2bf(f[i2]);   // transposed scalar write
    }
    __syncthreads();
    const int ro = t >> 2, co = (t & 3) << 4;
    short* dst = isK ? (ktg + base + (size_t)(tile * 64 + ro) * 64 + co)
                     : (vtg + base + (size_t)ro * LL + tile * 64 + co);
    *(short8*)(dst)     = *(const short8*)&Ts[ro * 64 + co];
    *(short8*)(dst + 8) = *(const short8*)&Ts[ro * 64 + co + 8];
  } else {
    // one 32-bit word per thread: 32 consecutive mask ints -> 32 bits
    const int w   = (bid - 2048) * 256 + t;
    const int b   = w >> 17;            // 131072 words per batch
    const int rem = w & 131071;         // row*64 + wordcol
    const int* src = mask + ((size_t)b << 22) + ((size_t)rem << 5);
    unsigned word = 0;
#pragma unroll
    for (int j = 0; j < 8; ++j) {
      int4v mi = *(const int4v*)(src + j * 4);
      word |= (mi.x != 0 ? 1u : 0u) << (j * 4);
      word |= (mi.y != 0 ? 1u : 0u) << (j * 4 + 1);
      word |= (mi.z != 0 ? 1u : 0u) << (j * 4 + 2);
      word |= (mi.w != 0 ? 1u : 0u) << (j * 4 + 3);
    }
    mp[w] = word;
  }
}

// ---------------- attention: flash-style, dbuf global_load_lds staging ------
__global__ __launch_bounds__(256, 4)
void attn_kernel(const float* __restrict__ q, const short* __restrict__ ktg,
                 const short* __restrict__ vtg, const unsigned* __restrict__ mp,
                 float* __restrict__ out) {
  __shared__ short Kt[2][BK * DD];     // [buf][e][d] swizzled, 8KB each
  __shared__ short Vt[2][DD * BK];     // [buf][d][key] swizzled, 8KB each
  __shared__ short Ps[4][16 * BK];     // per-wave P tile, swizzled

  const int t    = threadIdx.x;
  const int lane = t & 63;
  const int wq   = t >> 6;
  const int lo16 = lane & 15;
  const int hi4  = lane >> 4;

  const int bx = blockIdx.x;
  const int qt = bx & 31;
  const int hd = bx >> 5;
  const int b  = hd >> 4;
  const size_t base = (size_t)hd * LL * DD;
  const int q0 = qt * 64;

  // ---- Q straight to registers (bf16 fragments) ----
  short8 aq[2];
  {
    const float* qrow = q + base + (size_t)(q0 + wq * 16 + lo16) * DD;
#pragma unroll
    for (int s = 0; s < 2; ++s) {
      f32x4 f0 = *(const f32x4*)(qrow + s * 32 + hi4 * 8);
      f32x4 f1 = *(const f32x4*)(qrow + s * 32 + hi4 * 8 + 4);
      short8 a;
      a[0] = f2bf(f0.x); a[1] = f2bf(f0.y); a[2] = f2bf(f0.z); a[3] = f2bf(f0.w);
      a[4] = f2bf(f1.x); a[5] = f2bf(f1.y); a[6] = f2bf(f1.z); a[7] = f2bf(f1.w);
      aq[s] = a;
    }
  }

  // ---- staging source offsets (swizzle folded into the GLOBAL address) ----
  // LDS elem idx for this lane: wq*1024 + i*512 + lane*8  (global_load_lds
  // writes wave-uniform base + lane*16B, so LDS stays linear; rule 21)
  int kge[2], vge[2];
#pragma unroll
  for (int i = 0; i < 2; ++i) {
    int idx = wq * 1024 + i * 512 + lane * 8;
    int e = idx >> 6, c = idx & 63;
    kge[i] = e * DD + (c ^ ((e & 7) << 3));   // + kt*4096 per tile
    vge[i] = e * LL + (c ^ ((e & 7) << 3));   // row d=e, + kt*64 per tile
  }
  const short* kthead = ktg + base;
  const short* vthead = vtg + base;

  f32x4 O[4] = {};
  float m[4], lsum[4];
#pragma unroll
  for (int r = 0; r < 4; ++r) { m[r] = -INFINITY; lsum[r] = 0.f; }
  const float scale = 0.125f;

  const unsigned long long* mp64 =
      (const unsigned long long*)mp + (size_t)b * (LL * 32);

  // prologue: stage tile 0 into buf 0
#pragma unroll
  for (int i = 0; i < 2; ++i) {
    __builtin_amdgcn_global_load_lds((const AS1 uint32_t*)(kthead + kge[i]),
                                     (AS3 uint32_t*)&Kt[0][wq * 1024 + i * 512],
                                     16, 0, 0);
    __builtin_amdgcn_global_load_lds((const AS1 uint32_t*)(vthead + vge[i]),
                                     (AS3 uint32_t*)&Vt[0][wq * 1024 + i * 512],
                                     16, 0, 0);
  }
  __syncthreads();

  for (int kt2 = 0; kt2 < LL / BK; ++kt2) {
    const int cur = kt2 & 1;
    if (kt2 < LL / BK - 1) {
      const int nxt = kt2 + 1;
#pragma unroll
      for (int i = 0; i < 2; ++i) {
        __builtin_amdgcn_global_load_lds(
            (const AS1 uint32_t*)(kthead + nxt * 4096 + kge[i]),
            (AS3 uint32_t*)&Kt[cur ^ 1][wq * 1024 + i * 512], 16, 0, 0);
        __builtin_amdgcn_global_load_lds(
            (const AS1 uint32_t*)(vthead + nxt * 64 + vge[i]),
            (AS3 uint32_t*)&Vt[cur ^ 1][wq * 1024 + i * 512], 16, 0, 0);
      }
    }

    // ---- QK^T: S[16 q][64 e] ----
    f32x4 S[4];
#pragma unroll
    for (int sub = 0; sub < 4; ++sub) {
      f32x4 acc = {};
      int e  = sub * 16 + lo16;
      int sw = (e & 7) << 3;
#pragma unroll
      for (int s = 0; s < 2; ++s) {
        int c = s * 32 + hi4 * 8;
        short8 bk = *(const short8*)&Kt[cur][e * DD + (c ^ sw)];
        acc = __builtin_amdgcn_mfma_f32_16x16x32_bf16(aq[s], bk, acc, 0, 0, 0);
      }
      S[sub] = acc;
    }

    // ---- scale + mask from packed bits (one 8B load per q-row) ----
#pragma unroll
    for (int r = 0; r < 4; ++r) {
      int qg = q0 + wq * 16 + hi4 * 4 + r;
      unsigned long long mw = mp64[(size_t)qg * 32 + kt2];
      unsigned w0 = (unsigned)mw, w1 = (unsigned)(mw >> 32);
      unsigned t0 = w0 >> lo16, t1 = w1 >> lo16;
      S[0][r] = (t0 & 1)         ? S[0][r] * scale : NEGV;
      S[1][r] = ((t0 >> 16) & 1) ? S[1][r] * scale : NEGV;
      S[2][r] = (t1 & 1)         ? S[2][r] * scale : NEGV;
      S[3][r] = ((t1 >> 16) & 1) ? S[3][r] * scale : NEGV;
    }

    // ---- online softmax ----
    float mt[4];
#pragma unroll
    for (int r = 0; r < 4; ++r) {
      float x = fmaxf(fmaxf(S[0][r], S[1][r]), fmaxf(S[2][r], S[3][r]));
      x = fmaxf(x, __shfl_xor(x, 1));
      x = fmaxf(x, __shfl_xor(x, 2));
      x = fmaxf(x, __shfl_xor(x, 4));
      x = fmaxf(x, __shfl_xor(x, 8));
      mt[r] = x;
    }
#pragma unroll
    for (int r = 0; r < 4; ++r) {
      float mnew = fmaxf(m[r], mt[r]);
      float fac  = __expf(m[r] - mnew);
      m[r] = mnew;
      lsum[r] *= fac;
#pragma unroll
      for (int sub = 0; sub < 4; ++sub) O[sub][r] *= fac;
    }

    // ---- P -> bf16 -> per-wave LDS relayout (wave-private: no barrier) ----
#pragma unroll
    for (int sub = 0; sub < 4; ++sub) {
#pragma unroll
      for (int r = 0; r < 4; ++r) {
        float p = __expf(S[sub][r] - m[r]);
        lsum[r] += p;
        int qr = hi4 * 4 + r;
        int kg = sub * 16 + lo16;
        Ps[wq][qr * BK + (kg ^ ((qr & 7) << 3))] = f2bf(p);
      }
    }

    // ---- PV: O += P * V ----
    short8 ap[2];
    {
      int sw = (lo16 & 7) << 3;
#pragma unroll
      for (int s = 0; s < 2; ++s) {
        int c = s * 32 + hi4 * 8;
        ap[s] = *(const short8*)&Ps[wq][lo16 * BK + (c ^ sw)];
      }
    }
#pragma unroll
    for (int sub = 0; sub < 4; ++sub) {
      int d  = sub * 16 + lo16;
      int sw = (d & 7) << 3;
#pragma unroll
      for (int s = 0; s < 2; ++s) {
        int c = s * 32 + hi4 * 8;
        short8 bv = *(const short8*)&Vt[cur][d * BK + (c ^ sw)];
        O[sub] = __builtin_amdgcn_mfma_f32_16x16x32_bf16(ap[s], bv, O[sub], 0, 0, 0);
      }
    }

    __syncthreads();  // staged next-tile complete + all waves done with cur
  }

  // ---- epilogue ----
#pragma unroll
  for (int r = 0; r < 4; ++r) {
    float x = lsum[r];
    x += __shfl_xor(x, 1);
    x += __shfl_xor(x, 2);
    x += __shfl_xor(x, 4);
    x += __shfl_xor(x, 8);
    lsum[r] = 1.f / x;
  }
#pragma unroll
  for (int sub = 0; sub < 4; ++sub) {
#pragma unroll
    for (int r = 0; r < 4; ++r) {
      int qg = q0 + wq * 16 + hi4 * 4 + r;
      int dg = sub * 16 + lo16;
      out[base + (size_t)qg * DD + dg] = O[sub][r] * lsum[r];
    }
  }
}

extern "C" void kernel_launch(void* const* d_in, const int* in_sizes, int n_in,
                              void* d_out, int out_size, void* d_ws, size_t ws_size,
                              hipStream_t stream) {
  const float* q    = (const float*)d_in[0];
  const float* k    = (const float*)d_in[1];
  const float* v    = (const float*)d_in[2];
  const int*   mask = (const int*)d_in[3];
  float* out = (float*)d_out;

  // workspace carve: ktg (8.38MB) | vtg (8.38MB) | mp (1MB)
  short*    ktg = (short*)d_ws;
  short*    vtg = ktg + (size_t)32 * LL * DD;
  unsigned* mp  = (unsigned*)(vtg + (size_t)32 * LL * DD);

  prep_kernel<<<3072, 256, 0, stream>>>(k, v, mask, ktg, vtg, mp);
  attn_kernel<<<1024, 256, 0, stream>>>(q, ktg, vtg, mp, out);
}

// Round 4
// 85.882 us; speedup vs baseline: 2.0998x; 1.3481x over previous
//
#include <hip/hip_runtime.h>
#include <hip/hip_bf16.h>
#include <stdint.h>

#define LL 2048
#define DD 64
#define BK 64

typedef __attribute__((ext_vector_type(4))) float f32x4;
typedef __attribute__((ext_vector_type(8))) short short8;
typedef __attribute__((ext_vector_type(4))) short short4v;
typedef __attribute__((ext_vector_type(4))) int   int4v;

#define AS3 __attribute__((address_space(3)))
#define AS1 __attribute__((address_space(1)))

// fp32 -> bf16 round-to-nearest-even
__device__ __forceinline__ short f2bf(float f) {
  unsigned u = __builtin_bit_cast(unsigned, f);
  return (short)((u + 0x7fffu + ((u >> 16) & 1u)) >> 16);
}

// ---------------- prepass: K transpose, V transpose, mask bit-pack ----------
__global__ __launch_bounds__(256, 4)
void prep_kernel(const float* __restrict__ k, const float* __restrict__ v,
                 const int* __restrict__ mask, short* __restrict__ ktg,
                 short* __restrict__ vtg, unsigned* __restrict__ mp) {
  __shared__ short Ts[64 * 64];
  const int bid = blockIdx.x;
  const int t = threadIdx.x;

  if (bid < 2048) {
    const bool isK = (bid < 1024);
    const int id   = isK ? bid : bid - 1024;
    const int hd   = id >> 5;
    const int tile = id & 31;
    const size_t base = (size_t)hd * LL * DD;

    const int r  = t >> 2;
    const int c0 = (t & 3) << 4;
    const float* src = isK ? (k + base + (size_t)r * LL + tile * 64 + c0)
                           : (v + base + (size_t)(tile * 64 + r) * DD + c0);
#pragma unroll
    for (int j = 0; j < 16; j += 4) {
      f32x4 f = *(const f32x4*)(src + j);
#pragma unroll
      for (int i2 = 0; i2 < 4; ++i2)
        Ts[(c0 + j + i2) * 64 + r] = f2bf(f[i2]);
    }
    __syncthreads();
    const int ro = t >> 2, co = (t & 3) << 4;
    short* dst = isK ? (ktg + base + (size_t)(tile * 64 + ro) * 64 + co)
                     : (vtg + base + (size_t)ro * LL + tile * 64 + co);
    *(short8*)(dst)     = *(const short8*)&Ts[ro * 64 + co];
    *(short8*)(dst + 8) = *(const short8*)&Ts[ro * 64 + co + 8];
  } else {
    const int w   = (bid - 2048) * 256 + t;
    const int b   = w >> 17;
    const int rem = w & 131071;
    const int* src = mask + ((size_t)b << 22) + ((size_t)rem << 5);
    unsigned word = 0;
#pragma unroll
    for (int j = 0; j < 8; ++j) {
      int4v mi = *(const int4v*)(src + j * 4);
      word |= (mi.x != 0 ? 1u : 0u) << (j * 4);
      word |= (mi.y != 0 ? 1u : 0u) << (j * 4 + 1);
      word |= (mi.z != 0 ? 1u : 0u) << (j * 4 + 2);
      word |= (mi.w != 0 ? 1u : 0u) << (j * 4 + 3);
    }
    mp[w] = word;
  }
}

// ---------------- attention: no-max flash loop, swapped QK^T ----------------
__global__ __launch_bounds__(256, 4)
void attn_kernel(const float* __restrict__ q, const short* __restrict__ ktg,
                 const short* __restrict__ vtg, const unsigned* __restrict__ mp,
                 float* __restrict__ out) {
  __shared__ short Kt[2][BK * DD];           // [buf][e][d] swizzled
  __shared__ short Vt[2][DD * BK];           // [buf][d][key] swizzled
  __shared__ __align__(16) short Ps[4][16 * BK];  // per-wave P[q][key] swizzled

  const int t    = threadIdx.x;
  const int lane = t & 63;
  const int wq   = t >> 6;
  const int lo16 = lane & 15;
  const int hi4  = lane >> 4;

  const int bx = blockIdx.x;
  const int qt = bx & 31;
  const int hd = bx >> 5;
  const int b  = hd >> 4;
  const size_t base = (size_t)hd * LL * DD;
  const int q0 = qt * 64;

  // ---- Q to registers, pre-scaled by 0.125*log2(e) so P = exp2(S) ----
  short8 aq[2];
  {
    const float* qrow = q + base + (size_t)(q0 + wq * 16 + lo16) * DD;
    const float qsc = 0.125f * 1.44269504f;
#pragma unroll
    for (int s = 0; s < 2; ++s) {
      f32x4 f0 = *(const f32x4*)(qrow + s * 32 + hi4 * 8);
      f32x4 f1 = *(const f32x4*)(qrow + s * 32 + hi4 * 8 + 4);
      short8 a;
      a[0] = f2bf(f0.x * qsc); a[1] = f2bf(f0.y * qsc);
      a[2] = f2bf(f0.z * qsc); a[3] = f2bf(f0.w * qsc);
      a[4] = f2bf(f1.x * qsc); a[5] = f2bf(f1.y * qsc);
      a[6] = f2bf(f1.z * qsc); a[7] = f2bf(f1.w * qsc);
      aq[s] = a;
    }
  }

  // staging offsets: swizzle folded into GLOBAL source addr (LDS dest linear)
  int kge[2], vge[2];
#pragma unroll
  for (int i = 0; i < 2; ++i) {
    int idx = wq * 1024 + i * 512 + lane * 8;
    int e = idx >> 6, c = idx & 63;
    kge[i] = e * DD + (c ^ ((e & 7) << 3));
    vge[i] = e * LL + (c ^ ((e & 7) << 3));
  }
  const short* kthead = ktg + base;
  const short* vthead = vtg + base;

  f32x4 O[4] = {};
  float lsum = 0.f;

  // one 8B mask word per lane per tile: this lane's q-row
  const int qg = q0 + wq * 16 + lo16;
  const unsigned long long* mrow =
      (const unsigned long long*)mp + (size_t)b * (LL * 32) + (size_t)qg * 32;

  // prologue: stage tile 0 into buf 0
#pragma unroll
  for (int i = 0; i < 2; ++i) {
    __builtin_amdgcn_global_load_lds((const AS1 uint32_t*)(kthead + kge[i]),
                                     (AS3 uint32_t*)&Kt[0][wq * 1024 + i * 512],
                                     16, 0, 0);
    __builtin_amdgcn_global_load_lds((const AS1 uint32_t*)(vthead + vge[i]),
                                     (AS3 uint32_t*)&Vt[0][wq * 1024 + i * 512],
                                     16, 0, 0);
  }
  __syncthreads();

  for (int kt2 = 0; kt2 < LL / BK; ++kt2) {
    const int cur = kt2 & 1;
    if (kt2 < LL / BK - 1) {
      const int nxt = kt2 + 1;
#pragma unroll
      for (int i = 0; i < 2; ++i) {
        __builtin_amdgcn_global_load_lds(
            (const AS1 uint32_t*)(kthead + nxt * 4096 + kge[i]),
            (AS3 uint32_t*)&Kt[cur ^ 1][wq * 1024 + i * 512], 16, 0, 0);
        __builtin_amdgcn_global_load_lds(
            (const AS1 uint32_t*)(vthead + nxt * 64 + vge[i]),
            (AS3 uint32_t*)&Vt[cur ^ 1][wq * 1024 + i * 512], 16, 0, 0);
      }
    }

    // ---- swapped QK^T: S^T[key][q];  lane: q=lo16, keys=sub*16+hi4*4+r ----
    f32x4 S[4];
#pragma unroll
    for (int sub = 0; sub < 4; ++sub) {
      f32x4 acc = {};
      int e  = sub * 16 + lo16;
      int sw = (e & 7) << 3;
#pragma unroll
      for (int s = 0; s < 2; ++s) {
        int c = s * 32 + hi4 * 8;
        short8 bk = *(const short8*)&Kt[cur][e * DD + (c ^ sw)];
        acc = __builtin_amdgcn_mfma_f32_16x16x32_bf16(bk, aq[s], acc, 0, 0, 0);
      }
      S[sub] = acc;
    }

    // ---- mask bits for this lane's q-row ----
    unsigned long long mw = mrow[kt2];
    unsigned t0 = (unsigned)mw >> (hi4 * 4);
    unsigned t1 = (unsigned)(mw >> 32) >> (hi4 * 4);

    // ---- P = exp2(S) or 0; pack 4 consecutive keys -> ds_write_b64 ----
    const int psw = (lo16 & 7) << 3;
#pragma unroll
    for (int sub = 0; sub < 4; ++sub) {
      unsigned bits = (sub & 2) ? t1 : t0;
      int sh = (sub & 1) ? 16 : 0;
      short4v pk;
#pragma unroll
      for (int r = 0; r < 4; ++r) {
        float e = __builtin_amdgcn_exp2f(S[sub][r]);
        float p = ((bits >> (sh + r)) & 1u) ? e : 0.f;
        lsum += p;
        pk[r] = f2bf(p);
      }
      int kb = sub * 16 + hi4 * 4;
      *(short4v*)&Ps[wq][lo16 * BK + (kb ^ psw)] = pk;
    }

    // ---- PV: O[q][d] += P[q][key] V[key][d]  (Ps wave-private: no barrier) --
    short8 ap[2];
#pragma unroll
    for (int s = 0; s < 2; ++s)
      ap[s] = *(const short8*)&Ps[wq][lo16 * BK + ((s * 32 + hi4 * 8) ^ psw)];
#pragma unroll
    for (int sub = 0; sub < 4; ++sub) {
      int d  = sub * 16 + lo16;
      int sw = (d & 7) << 3;
#pragma unroll
      for (int s = 0; s < 2; ++s) {
        int c = s * 32 + hi4 * 8;
        short8 bv = *(const short8*)&Vt[cur][d * BK + (c ^ sw)];
        O[sub] = __builtin_amdgcn_mfma_f32_16x16x32_bf16(ap[s], bv, O[sub], 0, 0, 0);
      }
    }

    __syncthreads();  // next tile staged + all waves done with cur
  }

  // ---- epilogue: lsum reduce over hi4 groups, redistribute to O rows ----
  lsum += __shfl_xor(lsum, 16);
  lsum += __shfl_xor(lsum, 32);          // all lanes: Lsum(q = lo16)
  float linv[4];
#pragma unroll
  for (int r = 0; r < 4; ++r)
    linv[r] = 1.f / __shfl(lsum, hi4 * 4 + r);   // Lsum for O-row hi4*4+r

#pragma unroll
  for (int sub = 0; sub < 4; ++sub) {
#pragma unroll
    for (int r = 0; r < 4; ++r) {
      int qr = q0 + wq * 16 + hi4 * 4 + r;
      int dg = sub * 16 + lo16;
      out[base + (size_t)qr * DD + dg] = O[sub][r] * linv[r];
    }
  }
}

extern "C" void kernel_launch(void* const* d_in, const int* in_sizes, int n_in,
                              void* d_out, int out_size, void* d_ws, size_t ws_size,
                              hipStream_t stream) {
  const float* q    = (const float*)d_in[0];
  const float* k    = (const float*)d_in[1];
  const float* v    = (const float*)d_in[2];
  const int*   mask = (const int*)d_in[3];
  float* out = (float*)d_out;

  short*    ktg = (short*)d_ws;
  short*    vtg = ktg + (size_t)32 * LL * DD;
  unsigned* mp  = (unsigned*)(vtg + (size_t)32 * LL * DD);

  prep_kernel<<<3072, 256, 0, stream>>>(k, v, mask, ktg, vtg, mp);
  attn_kernel<<<1024, 256, 0, stream>>>(q, ktg, vtg, mp, out);
}

// Round 5
// 81.664 us; speedup vs baseline: 2.2083x; 1.0517x over previous
//
#include <hip/hip_runtime.h>
#include <hip/hip_bf16.h>
#include <stdint.h>

#define LL 2048
#define DD 64

typedef __attribute__((ext_vector_type(4))) float    f32x4;
typedef __attribute__((ext_vector_type(16))) float   f32x16;
typedef __attribute__((ext_vector_type(8))) short    short8;
typedef __attribute__((ext_vector_type(4))) int      int4v;
typedef __attribute__((ext_vector_type(4))) unsigned uint4v;

#define AS3 __attribute__((address_space(3)))
#define AS1 __attribute__((address_space(1)))

// fp32 -> bf16 round-to-nearest-even
__device__ __forceinline__ short f2bf(float f) {
  unsigned u = __builtin_bit_cast(unsigned, f);
  return (short)((u + 0x7fffu + ((u >> 16) & 1u)) >> 16);
}

// packed fp32x2 -> bf16x2 (RNE), one instruction
__device__ __forceinline__ unsigned cvtpk(float lo, float hi) {
  unsigned r;
  asm("v_cvt_pk_bf16_f32 %0, %1, %2" : "=v"(r) : "v"(lo), "v"(hi));
  return r;
}
// swap: a.hi32lanes <-> b.lo32lanes  => a=[a_lo,b_lo], b=[a_hi,b_hi]
__device__ __forceinline__ void plswap(unsigned &a, unsigned &b) {
  asm volatile("v_permlane32_swap_b32 %0, %1" : "+v"(a), "+v"(b));
}

// ---------------- prepass: K transpose, V transpose, mask bit-pack ----------
__global__ __launch_bounds__(256, 4)
void prep_kernel(const float* __restrict__ k, const float* __restrict__ v,
                 const int* __restrict__ mask, short* __restrict__ ktg,
                 short* __restrict__ vtg, unsigned* __restrict__ mp) {
  __shared__ short Ts[64 * 64];
  const int bid = blockIdx.x;
  const int t = threadIdx.x;

  if (bid < 2048) {
    const bool isK = (bid < 1024);
    const int id   = isK ? bid : bid - 1024;
    const int hd   = id >> 5;
    const int tile = id & 31;
    const size_t base = (size_t)hd * LL * DD;

    const int r  = t >> 2;
    const int c0 = (t & 3) << 4;
    const float* src = isK ? (k + base + (size_t)r * LL + tile * 64 + c0)
                           : (v + base + (size_t)(tile * 64 + r) * DD + c0);
#pragma unroll
    for (int j = 0; j < 16; j += 4) {
      f32x4 f = *(const f32x4*)(src + j);
#pragma unroll
      for (int i2 = 0; i2 < 4; ++i2)
        Ts[(c0 + j + i2) * 64 + r] = f2bf(f[i2]);
    }
    __syncthreads();
    const int ro = t >> 2, co = (t & 3) << 4;
    short* dst = isK ? (ktg + base + (size_t)(tile * 64 + ro) * 64 + co)
                     : (vtg + base + (size_t)ro * LL + tile * 64 + co);
    *(short8*)(dst)     = *(const short8*)&Ts[ro * 64 + co];
    *(short8*)(dst + 8) = *(const short8*)&Ts[ro * 64 + co + 8];
  } else {
    const int w   = (bid - 2048) * 256 + t;
    const int b   = w >> 17;
    const int rem = w & 131071;            // row*64 + wordcol
    const int* src = mask + ((size_t)b << 22) + ((size_t)rem << 5);
    unsigned word = 0;
#pragma unroll
    for (int j = 0; j < 8; ++j) {
      int4v mi = *(const int4v*)(src + j * 4);
      word |= (mi.x != 0 ? 1u : 0u) << (j * 4);
      word |= (mi.y != 0 ? 1u : 0u) << (j * 4 + 1);
      word |= (mi.z != 0 ? 1u : 0u) << (j * 4 + 2);
      word |= (mi.w != 0 ? 1u : 0u) << (j * 4 + 3);
    }
    const int row = rem >> 6, wc = rem & 63;
    // tile-major layout: [b][kt=wc>>1][row][half=wc&1]
    mp[((size_t)b << 17) + (size_t)(wc >> 1) * 4096 + row * 2 + (wc & 1)] = word;
  }
}

// -------- attention: 32x32 MFMA, q=32/wave, in-register P via permlane ------
__global__ __launch_bounds__(256, 2)
void attn_kernel(const float* __restrict__ q, const short* __restrict__ ktg,
                 const short* __restrict__ vtg, const unsigned* __restrict__ mp,
                 float* __restrict__ out) {
  // fragment-major LDS: chunk = fragid*64 + lane, 16B each; reads = base+lane*16+imm
  __shared__ short KtF[2][4096];   // frag (kh*4+step): K[key=kh*32+l31][d=step*16+g*8+j]
  __shared__ short VtF[2][4096];   // frag (stg*2+dh):  V[key=stg*16+g*8+j][dv=dh*32+l31]

  const int t = threadIdx.x, lane = t & 63, wq = t >> 6;
  const int l31 = lane & 31, g = lane >> 5;

  // XCD swizzle: 16 consecutive logical blocks (one head) per XCD
  const int lg = ((blockIdx.x & 7) << 6) + (blockIdx.x >> 3);
  const int qt = lg & 15, hd = lg >> 4, b = hd >> 4;
  const size_t base = (size_t)hd * LL * DD;
  const int q0 = qt * 128 + wq * 32;          // this wave's first q row

  // ---- Q B-fragments (pre-scaled by 0.125*log2e): B[k=d][n=q=l31] ----
  short8 bq[4];
  {
    const float qsc = 0.125f * 1.44269504f;
    const float* qp = q + base + (size_t)(q0 + l31) * DD + g * 8;
#pragma unroll
    for (int s = 0; s < 4; ++s) {
      f32x4 f0 = *(const f32x4*)(qp + s * 16);
      f32x4 f1 = *(const f32x4*)(qp + s * 16 + 4);
      uint4v u;
      u.x = cvtpk(f0.x * qsc, f0.y * qsc);
      u.y = cvtpk(f0.z * qsc, f0.w * qsc);
      u.z = cvtpk(f1.x * qsc, f1.y * qsc);
      u.w = cvtpk(f1.z * qsc, f1.w * qsc);
      bq[s] = __builtin_bit_cast(short8, u);
    }
  }

  // ---- staging source offsets (fragment decode done once) ----
  int kge0, kge1, vge0, vge1;
  {
    int cid0 = wq * 128 + lane, cid1 = cid0 + 64;
    int r0 = cid0 & 31, g0 = (cid0 >> 5) & 1, r1 = cid1 & 31, g1 = (cid1 >> 5) & 1;
    kge0 = ((cid0 >> 8) * 32 + r0) * DD + ((cid0 >> 6) & 3) * 16 + g0 * 8;
    kge1 = ((cid1 >> 8) * 32 + r1) * DD + ((cid1 >> 6) & 3) * 16 + g1 * 8;
    vge0 = (((cid0 >> 6) & 1) * 32 + r0) * LL + (cid0 >> 7) * 16 + g0 * 8;
    vge1 = (((cid1 >> 6) & 1) * 32 + r1) * LL + (cid1 >> 7) * 16 + g1 * 8;
  }
  const short* kthead = ktg + base;
  const short* vthead = vtg + base;

#define STAGE(buf, kt) do { \
  __builtin_amdgcn_global_load_lds((const AS1 uint32_t*)(kthead + (kt)*4096 + kge0), \
      (AS3 uint32_t*)&KtF[buf][(wq*128)*8],    16, 0, 0); \
  __builtin_amdgcn_global_load_lds((const AS1 uint32_t*)(kthead + (kt)*4096 + kge1), \
      (AS3 uint32_t*)&KtF[buf][(wq*128+64)*8], 16, 0, 0); \
  __builtin_amdgcn_global_load_lds((const AS1 uint32_t*)(vthead + (kt)*64 + vge0), \
      (AS3 uint32_t*)&VtF[buf][(wq*128)*8],    16, 0, 0); \
  __builtin_amdgcn_global_load_lds((const AS1 uint32_t*)(vthead + (kt)*64 + vge1), \
      (AS3 uint32_t*)&VtF[buf][(wq*128+64)*8], 16, 0, 0); \
} while (0)

  f32x16 o0 = {}, o1 = {};
  float lsum = 0.f;

  const unsigned long long* mp64 = (const unsigned long long*)mp;
  const size_t mbase = (size_t)b * 65536 + (size_t)(q0 + l31);  // + kt*2048

  STAGE(0, 0);
  __syncthreads();

  for (int kt = 0; kt < LL / 64; ++kt) {
    const int cur = kt & 1;
    if (kt < LL / 64 - 1) STAGE(cur ^ 1, kt + 1);

    // ---- QK^T (swapped): S^T[key][q], acc col = q = l31 ----
    f32x16 s0 = {}, s1 = {};
    __builtin_amdgcn_s_setprio(1);
#pragma unroll
    for (int st = 0; st < 4; ++st) {
      short8 ka = *(const short8*)&KtF[cur][(st * 64 + lane) * 8];
      short8 kb = *(const short8*)&KtF[cur][((st + 4) * 64 + lane) * 8];
      s0 = __builtin_amdgcn_mfma_f32_32x32x16_bf16(ka, bq[st], s0, 0, 0, 0);
      s1 = __builtin_amdgcn_mfma_f32_32x32x16_bf16(kb, bq[st], s1, 0, 0, 0);
    }
    __builtin_amdgcn_s_setprio(0);

    const unsigned long long mw = mp64[mbase + (size_t)kt * 2048];

#pragma unroll
    for (int kh = 0; kh < 2; ++kh) {
      const unsigned th = (unsigned)(mw >> (kh * 32)) >> (g * 4);
      const f32x16 sv = kh ? s1 : s0;
      // key of acc reg r: kh*32 + (r&3) + 8*(r>>2) + 4*g
      float pv_[16];
#pragma unroll
      for (int r = 0; r < 16; ++r) {
        const unsigned bit = 1u << ((r & 3) + 8 * (r >> 2));
        float e = __builtin_amdgcn_exp2f(sv[r]);
        float p = (th & bit) ? e : 0.f;
        lsum += p;
        pv_[r] = p;
      }
      unsigned cc0 = cvtpk(pv_[0],  pv_[1]),  cc1 = cvtpk(pv_[2],  pv_[3]);
      unsigned cc2 = cvtpk(pv_[4],  pv_[5]),  cc3 = cvtpk(pv_[6],  pv_[7]);
      unsigned cc4 = cvtpk(pv_[8],  pv_[9]),  cc5 = cvtpk(pv_[10], pv_[11]);
      unsigned cc6 = cvtpk(pv_[12], pv_[13]), cc7 = cvtpk(pv_[14], pv_[15]);
      // assemble PV A-frags: rows q=l31, k-elems = keys g*8+j (+16 per step)
      plswap(cc0, cc2); plswap(cc1, cc3);
      plswap(cc4, cc6); plswap(cc5, cc7);
      short8 pa0 = __builtin_bit_cast(short8, (uint4v){cc0, cc1, cc2, cc3});
      short8 pa1 = __builtin_bit_cast(short8, (uint4v){cc4, cc5, cc6, cc7});
      __builtin_amdgcn_s_setprio(1);
#pragma unroll
      for (int s = 0; s < 2; ++s) {
        short8 pa = s ? pa1 : pa0;
        int stg = kh * 2 + s;
        short8 v0 = *(const short8*)&VtF[cur][((stg * 2 + 0) * 64 + lane) * 8];
        short8 v1 = *(const short8*)&VtF[cur][((stg * 2 + 1) * 64 + lane) * 8];
        o0 = __builtin_amdgcn_mfma_f32_32x32x16_bf16(pa, v0, o0, 0, 0, 0);
        o1 = __builtin_amdgcn_mfma_f32_32x32x16_bf16(pa, v1, o1, 0, 0, 0);
      }
      __builtin_amdgcn_s_setprio(0);
    }
    __syncthreads();   // staged buf^1 complete + all waves done with cur
  }

  // ---- epilogue: combine key-halves, normalize, store ----
  lsum += __shfl_xor(lsum, 32);        // full lsum for q = l31, all lanes
  float linv = 1.f / lsum;
  float* obase = out + base + (size_t)q0 * DD;
#pragma unroll
  for (int r = 0; r < 16; ++r) {
    int crow = (r & 3) + 8 * (r >> 2) + 4 * g;   // q row of acc reg r
    float li = __shfl(linv, crow);
    obase[(size_t)crow * DD + l31]      = o0[r] * li;
    obase[(size_t)crow * DD + 32 + l31] = o1[r] * li;
  }
}

extern "C" void kernel_launch(void* const* d_in, const int* in_sizes, int n_in,
                              void* d_out, int out_size, void* d_ws, size_t ws_size,
                              hipStream_t stream) {
  const float* q    = (const float*)d_in[0];
  const float* k    = (const float*)d_in[1];
  const float* v    = (const float*)d_in[2];
  const int*   mask = (const int*)d_in[3];
  float* out = (float*)d_out;

  short*    ktg = (short*)d_ws;
  short*    vtg = ktg + (size_t)32 * LL * DD;
  unsigned* mp  = (unsigned*)(vtg + (size_t)32 * LL * DD);

  prep_kernel<<<3072, 256, 0, stream>>>(k, v, mask, ktg, vtg, mp);
  attn_kernel<<<512, 256, 0, stream>>>(q, ktg, vtg, mp, out);
}